// Round 13
// baseline (710.083 us; speedup 1.0000x reference)
//
#include <hip/hip_runtime.h>
#include <hip/hip_bf16.h>

#define NE 512

// ---------------- static device buffers ----------------
__device__ __align__(16) float g_sv0[NE*64];
__device__ __align__(16) float g_sv[2][NE*256];
__device__ __align__(16) float g_pu4[NE*4];
__device__ __align__(16) float g_pd4[NE*4];
__device__ __align__(16) float g_puL[4*NE*64];       // per-layer p-means (u)
__device__ __align__(16) float g_pdL[4*NE*64];       // per-layer p-means (d)
__device__ __align__(16) float g_su0[64];
__device__ __align__(16) float g_sd0[64];
__device__ __align__(16) float g_su[256];
__device__ __align__(16) float g_sd[256];
__device__ __align__(16) float g_part4[4*16*NE*64];  // per-(layer,chunk,j,c) partials
__device__ __align__(16) float g_f[NE];
__device__ __align__(16) float g_hu[256*256];
__device__ __align__(16) float g_hd[256*256];
__device__ __align__(16) float g_orbu[256*256];
__device__ __align__(16) float g_orbd[256*256];
__device__ float g_logs[2];

__device__ __forceinline__ float tanh_fast(float x) {
  float e = __expf(2.f * x);
  return 1.f - 2.f / (e + 1.f);
}

// ---------------- K0 fused: pmean0 (all blocks) + geometry/s_v0/f (block 0) ----------
__global__ __launch_bounds__(256) void k_pgeom(const float* __restrict__ r,
                                               const float* __restrict__ a) {
  int j = blockIdx.x, t = threadIdx.x;
  if (j == 0) {
    for (int h = 0; h < 2; ++h) {
      int e = h*256 + t;
      float rx = r[3*e], ry = r[3*e+1], rz = r[3*e+2];
      float facc = 0.f;
      #pragma unroll
      for (int at = 0; at < 16; ++at) {
        float dx = rx - a[3*at], dy = ry - a[3*at+1], dz = rz - a[3*at+2];
        float len = sqrtf(dx*dx + dy*dy + dz*dz);
        g_sv0[e*64 + 4*at + 0] = dx;
        g_sv0[e*64 + 4*at + 1] = dy;
        g_sv0[e*64 + 4*at + 2] = dz;
        g_sv0[e*64 + 4*at + 3] = len;
        facc += expf(-len);
      }
      g_f[e] = facc;
    }
    __syncthreads();
    if (t < 128) {
      int h = t >> 6, c = t & 63;
      float s = 0.f;
      for (int i = 0; i < 256; ++i) s += g_sv0[(h*256 + i)*64 + c];
      (h ? g_sd0 : g_su0)[c] = s * (1.f/256.f);
    }
    __syncthreads();
  }
  float rjx = r[3*j], rjy = r[3*j+1], rjz = r[3*j+2];
  __shared__ float red[4][4];
  for (int h = 0; h < 2; ++h) {
    int i = h*256 + t;
    float dx = rjx - r[3*i], dy = rjy - r[3*i+1], dz = rjz - r[3*i+2];
    float ee = (i == j) ? 1.f : 0.f;
    float ex = dx+ee, ey = dy+ee, ez = dz+ee;
    float len = sqrtf(ex*ex + ey*ey + ez*ez);
    float v0 = dx, v1 = dy, v2 = dz, v3 = len;
    #pragma unroll
    for (int m = 1; m < 64; m <<= 1) {
      v0 += __shfl_xor(v0, m); v1 += __shfl_xor(v1, m);
      v2 += __shfl_xor(v2, m); v3 += __shfl_xor(v3, m);
    }
    if ((t & 63) == 0) {
      int wv = t >> 6;
      red[wv][0]=v0; red[wv][1]=v1; red[wv][2]=v2; red[wv][3]=v3;
    }
    __syncthreads();
    if (t == 0) {
      float* dst = h ? g_pd4 : g_pu4;
      #pragma unroll
      for (int c = 0; c < 4; ++c)
        dst[j*4 + c] = (red[0][c]+red[1][c]+red[2][c]+red[3][c]) * (1.f/256.f);
    }
    __syncthreads();
  }
}

// ---------------- fused 4-layer p-chain (no HBM p buffers at all) ----------------
__global__ __launch_bounds__(256, 4) void k_pchain(const float* __restrict__ W0,
                                                   const float* __restrict__ b0,
                                                   const float* __restrict__ Wr,
                                                   const float* __restrict__ brs,
                                                   const float* __restrict__ r) {
  __shared__ __align__(16) float xbuf[4][32*64];     // 32KB/block
  int t = threadIdx.x, lane = t & 63, wv = t >> 6;
  int gw = blockIdx.x*4 + wv;          // 0..8191
  int j = gw >> 4, chunk = gw & 15;    // 16 chunks of 32 rows
  int i0 = chunk * 32;
  float* xb = xbuf[wv];
  float rjx = r[3*j], rjy = r[3*j+1], rjz = r[3*j+2];
  float macc0 = 0.f, macc1 = 0.f, macc2 = 0.f, macc3 = 0.f;
  {
    float w0 = W0[lane], w1 = W0[64+lane], w2 = W0[128+lane], w3 = W0[192+lane];
    float bb = b0[lane];
    for (int ii = 0; ii < 32; ++ii) {
      int i = i0 + ii;
      float dx = rjx - r[3*i], dy = rjy - r[3*i+1], dz = rjz - r[3*i+2];
      float ee = (i == j) ? 1.f : 0.f;
      float ex = dx+ee, ey = dy+ee, ez = dz+ee;
      float len = sqrtf(ex*ex + ey*ey + ez*ez);
      float y = tanh_fast(bb + dx*w0 + dy*w1 + dz*w2 + len*w3);
      xb[ii*64 + lane] = y;
      macc0 += y;
    }
  }
  for (int l = 0; l < 3; ++l) {
    const float* W = Wr + l*4096;
    float wcol[64];
    #pragma unroll
    for (int k = 0; k < 64; ++k) wcol[k] = W[k*64 + lane];
    float bb = brs[l*64 + lane];
    float mac = 0.f;
    for (int ii = 0; ii < 32; ++ii) {
      const float* row = &xb[ii*64];
      float x = row[lane];
      float acc = bb;
      #pragma unroll
      for (int g = 0; g < 16; ++g) {
        float4 pv = *(const float4*)&row[4*g];       // wave-uniform broadcast
        acc += pv.x*wcol[4*g] + pv.y*wcol[4*g+1] + pv.z*wcol[4*g+2] + pv.w*wcol[4*g+3];
      }
      float y = tanh_fast(acc) + x;
      xb[ii*64 + lane] = y;
      mac += y;
    }
    if (l == 0) macc1 = mac;
    else if (l == 1) macc2 = mac;
    else macc3 = mac;
  }
  int base = chunk*(NE*64) + j*64 + lane;
  g_part4[0*(16*NE*64) + base] = macc0;
  g_part4[1*(16*NE*64) + base] = macc1;
  g_part4[2*(16*NE*64) + base] = macc2;
  g_part4[3*(16*NE*64) + base] = macc3;
}

// ---------------- finalize all 4 layers' p-means ----------------
__global__ __launch_bounds__(256) void k_reduce_p() {
  int idx = blockIdx.x*256 + threadIdx.x;   // 0..262143
  int l = idx >> 16;
  int rem = idx & 65535;
  int half = rem >> 15;
  int r2 = rem & 32767;
  int j = r2 >> 6, c = r2 & 63;
  const float* pp = g_part4 + l*(16*NE*64) + half*(8*NE*64) + j*64 + c;
  float s = 0.f;
  #pragma unroll
  for (int ch = 0; ch < 8; ++ch) s += pp[ch*(NE*64)];
  (half ? g_pdL : g_puL)[l*(NE*64) + j*64 + c] = s * (1.f/256.f);
}

// ---------------- s_v column means ----------------
__global__ __launch_bounds__(256) void k_smean(int svsel) {
  int h = blockIdx.x, t = threadIdx.x;
  const float* sv = g_sv[svsel];
  float s = 0.f;
  for (int i = 0; i < 256; ++i) s += sv[(h*256 + i)*256 + t];
  (h ? g_sd : g_su)[t] = s * (1.f/256.f);
}

// ---------------- s-channel matmul ----------------
// which: 0=layer0, 1..3=layer l, 4=FUSED heads (grp=rg>>3), 6=FUSED orbitals
template<int PUK, int SVK, int MEANK>
__global__ __launch_bounds__(256) void k_smm(int which, const float* __restrict__ W,
                                             const float* __restrict__ Wb,
                                             const float* __restrict__ W2,
                                             const float* __restrict__ Wb2,
                                             int pl) {
  constexpr int MAINK = 2*PUK + SVK;
  __shared__ __align__(16) float wsl[MAINK*32];
  __shared__ float insl[32*(MAINK+1)];
  __shared__ float biasv[32];
  __shared__ float bred[256];
  const float *pu_p=nullptr, *pd_p=nullptr, *sv_p=nullptr, *su_p=nullptr, *sd_p=nullptr;
  const float *res_p=nullptr, *rs_p=nullptr;
  float* out_p = nullptr;
  int t = threadIdx.x;
  int rg = blockIdx.x, cg = blockIdx.y;
  int grp = 0, rgl = rg;
  if (which >= 4) { grp = rg >> 3; rgl = rg & 7; }
  const float* Wsel = (which >= 4 && grp) ? W2 : W;
  const float* Wbsel = (which >= 4 && grp) ? Wb2 : Wb;
  int in_base = 0, dotanh = 1;
  switch (which) {
    case 0: pu_p=g_pu4; pd_p=g_pd4; su_p=g_su0; sd_p=g_sd0; sv_p=g_sv0;
            out_p=g_sv[0]; in_base=rg*32; break;
    case 1: case 2: case 3:
      pu_p=g_puL + pl*(NE*64); pd_p=g_pdL + pl*(NE*64); su_p=g_su; sd_p=g_sd;
      sv_p=g_sv[(which+1)&1]; res_p=sv_p; out_p=g_sv[which&1]; in_base=rg*32; break;
    case 4: pu_p=g_puL + pl*(NE*64); pd_p=g_pdL + pl*(NE*64); su_p=g_su; sd_p=g_sd;
            sv_p=g_sv[1]; out_p = grp ? g_hd : g_hu; in_base = grp*256 + rgl*32; break;
    default: sv_p = grp ? g_hd : g_hu; out_p = grp ? g_orbd : g_orbu;
             rs_p = g_f + grp*256; in_base = rgl*32; dotanh = 0; break;
  }
  int out_base = (which >= 4) ? rgl*32 : rg*32;
  int col0 = cg * 32;
  for (int idx = t; idx < MAINK*32; idx += 256) {
    int c = idx >> 5, cl = idx & 31;
    wsl[idx] = Wsel[(2*MEANK + c)*256 + col0 + cl];
  }
  for (int rr = 0; rr < 32; ++rr) {
    int row = in_base + rr;
    for (int c = t; c < MAINK; c += 256) {
      float v;
      if (c < PUK) v = pu_p[row*PUK + c];
      else if (c < 2*PUK) v = pd_p[row*PUK + (c - PUK)];
      else v = sv_p[row*SVK + (c - 2*PUK)];
      insl[rr*(MAINK+1) + c] = v;
    }
  }
  {
    int pcol = t & 31, ps = t >> 5;
    float bacc = 0.f;
    if (MEANK > 0) {
      for (int c = ps; c < MEANK; c += 8)
        bacc += su_p[c]*Wsel[c*256 + col0 + pcol] + sd_p[c]*Wsel[(MEANK + c)*256 + col0 + pcol];
    }
    bred[ps*32 + pcol] = bacc;
  }
  __syncthreads();
  if (t < 32) {
    float s = Wbsel[col0 + t];
    #pragma unroll
    for (int p8 = 0; p8 < 8; ++p8) s += bred[p8*32 + t];
    biasv[t] = s;
  }
  __syncthreads();
  int c4 = t & 7, rl = t >> 3;
  float a0 = biasv[4*c4], a1 = biasv[4*c4+1], a2 = biasv[4*c4+2], a3 = biasv[4*c4+3];
  const float* inrow = &insl[rl*(MAINK+1)];
  #pragma unroll 4
  for (int c = 0; c < MAINK; ++c) {
    float iv = inrow[c];
    float4 wv = *(const float4*)&wsl[c*32 + 4*c4];
    a0 += iv*wv.x; a1 += iv*wv.y; a2 += iv*wv.z; a3 += iv*wv.w;
  }
  int rowA = out_base + rl;
  int col = col0 + 4*c4;
  if (dotanh) { a0=tanh_fast(a0); a1=tanh_fast(a1); a2=tanh_fast(a2); a3=tanh_fast(a3); }
  if (res_p) {
    float4 rv = *(const float4*)&res_p[rowA*256 + col];
    a0 += rv.x; a1 += rv.y; a2 += rv.z; a3 += rv.w;
  }
  if (rs_p) { float fsc = rs_p[rowA]; a0*=fsc; a1*=fsc; a2*=fsc; a3*=fsc; }
  float4 ov; ov.x=a0; ov.y=a1; ov.z=a2; ov.w=a3;
  *(float4*)&out_p[rowA*256 + col] = ov;
}

// ---------------- register-resident LU, v9 ----------------
// v8.1 (260us) chain: bar -> colbuf read -> DPP search (all threads) -> readlane piv
// -> mults -> publish/extract -> bar, with 128-FMA bulk UPD squeezed pre-barrier.
// v9 cuts the chain two ways:
//  (1) search moves INTO the extract-owner half-wave (it holds col k+1 in regs):
//      8 local candidates + 5-step DPP PAIR-reduce {packed key, exact val};
//      its local lane 31 posts (p,piv) to LDS scalars pre-barrier. Other threads
//      never search.
//  (2) bulk rank-1 UPD(k-1) is deferred one region: registers carry updates <=k-2;
//      publish applies its single pending inline (16 FMA), extract applies two
//      pendings inline (mp via prow(k-1), m via readlane of publisher's P).
//      Bulk UPD then runs AFTER the LDS writes, off the inter-wave chain.
// PR/P zero-initialized so k==0 needs no guards and regalloc stays uniform.
#define REP8(M) M(0) M(1) M(2) M(3) M(4) M(5) M(6) M(7)

__global__ __launch_bounds__(512, 2) void k_lu() {
  __shared__ __align__(16) float colbuf[2][256];
  __shared__ __align__(16) float prowbuf[2][16*20];
  __shared__ unsigned scal_p[2];
  __shared__ float scal_v[2];
  const float* A = (blockIdx.x == 0) ? g_orbu : g_orbd;
  int t = threadIdx.x;
  int tile_c = t >> 5;        // 0..15 -> cols 16*tile_c .. +15 (half-wave group)
  int tile_r = t & 31;        // 0..31 -> rows 8*tile_r .. +7
  int lane = t & 63;
  int br = tile_r * 8;
  int pb = tile_c * 20;
  const float4* Ap = (const float4*)(A + br*256 + tile_c*16);
#define DECLROW(R) float4 M##R##_0 = Ap[R*64+0], M##R##_1 = Ap[R*64+1], \
                          M##R##_2 = Ap[R*64+2], M##R##_3 = Ap[R*64+3];
  REP8(DECLROW)
#undef DECLROW
  unsigned um8 = 0;
#define DPAIR(CTRL) { unsigned ko = (unsigned)__builtin_amdgcn_update_dpp(0, (int)key, CTRL, 0xf, 0xf, true); \
                      unsigned vo = (unsigned)__builtin_amdgcn_update_dpp(0, (int)__float_as_uint(val), CTRL, 0xf, 0xf, true); \
                      if (ko > key) { key = ko; val = __uint_as_float(vo); } }
#define CAND(RR) { unsigned kk = (um8 & (1u<<RR)) ? 0u : ((__float_as_uint(fabsf(e##RR)) & 0xFFFFFF00u) | (unsigned)(br + RR)); \
                   if (kk > key) { key = kk; val = e##RR; } }
  // ---- pre-loop: group 0 extracts + searches column 0 ----
  if (tile_c == 0) {
    float e0 = M0_0.x, e1 = M1_0.x, e2 = M2_0.x, e3 = M3_0.x;
    float e4 = M4_0.x, e5 = M5_0.x, e6 = M6_0.x, e7 = M7_0.x;
    float4 w0; w0.x=e0; w0.y=e1; w0.z=e2; w0.w=e3;
    float4 w1; w1.x=e4; w1.y=e5; w1.z=e6; w1.w=e7;
    *(float4*)&colbuf[0][br] = w0;
    *(float4*)&colbuf[0][br+4] = w1;
    unsigned key = 0; float val = 0.f;
    REP8(CAND)
    DPAIR(0x111) DPAIR(0x112) DPAIR(0x114) DPAIR(0x118) DPAIR(0x142)
    if (tile_r == 31) { scal_p[0] = key & 255u; scal_v[0] = val; }
  }
  __syncthreads();
  float prod = 1.f;
  int esum = 0;
  float mp0=0,mp1=0,mp2=0,mp3=0,mp4=0,mp5=0,mp6=0,mp7=0;
  for (int k = 0; k < 256; ++k) {
    int buf = k & 1;
    unsigned pk = scal_p[buf];
    float piv = scal_v[buf];
    int ee; float mant = frexpf(fabsf(piv), &ee);
    prod *= mant; esum += ee;
    if ((k & 31) == 31) { int e2n; prod = frexpf(prod, &e2n); esum += e2n; }
    if ((int)(pk >> 3) == tile_r) um8 |= 1u << (pk & 7);
    if (k == 255) break;
    float rp = 1.0f / piv;
    float4 c0 = *(const float4*)&colbuf[buf][br];
    float4 c1 = *(const float4*)&colbuf[buf][br+4];
    float m0 = c0.x*rp, m1 = c0.y*rp, m2 = c0.z*rp, m3 = c0.w*rp;
    float m4 = c1.x*rp, m5 = c1.y*rp, m6 = c1.z*rp, m7 = c1.w*rp;
    bool alive = (tile_c*16 + 15) >= (k + 1);
    float4 PR0, PR1, PR2, PR3;
    PR0.x=PR0.y=PR0.z=PR0.w=0.f; PR1=PR0; PR2=PR0; PR3=PR0;
    bool havePR = (k > 0) && alive;
    if (havePR) {
      const float* pwp = &prowbuf[buf^1][pb];
      PR0 = *(const float4*)&pwp[0];
      PR1 = *(const float4*)&pwp[4];
      PR2 = *(const float4*)&pwp[8];
      PR3 = *(const float4*)&pwp[12];
    }
    float4 P0, P1, P2, P3;
    P0.x=P0.y=P0.z=P0.w=0.f; P1=P0; P2=P0; P3=P0;
    // ---- publish pivot row k slice (with inline pending k-1 fix) ----
    if (alive && (int)(pk >> 3) == tile_r) {
      float mpsel = 0.f;
      switch (pk & 7) {
#define PSELR(R) case R: P0=M##R##_0; P1=M##R##_1; P2=M##R##_2; P3=M##R##_3; mpsel=mp##R; break;
        REP8(PSELR)
#undef PSELR
      }
      P0.x -= mpsel*PR0.x; P0.y -= mpsel*PR0.y; P0.z -= mpsel*PR0.z; P0.w -= mpsel*PR0.w;
      P1.x -= mpsel*PR1.x; P1.y -= mpsel*PR1.y; P1.z -= mpsel*PR1.z; P1.w -= mpsel*PR1.w;
      P2.x -= mpsel*PR2.x; P2.y -= mpsel*PR2.y; P2.z -= mpsel*PR2.z; P2.w -= mpsel*PR2.w;
      P3.x -= mpsel*PR3.x; P3.y -= mpsel*PR3.y; P3.z -= mpsel*PR3.z; P3.w -= mpsel*PR3.w;
      float* pw_ = &prowbuf[buf][pb];
      *(float4*)&pw_[0]  = P0;
      *(float4*)&pw_[4]  = P1;
      *(float4*)&pw_[8]  = P2;
      *(float4*)&pw_[12] = P3;
    }
    // ---- extract column k+1 (owner group): two inline pendings + search ----
    int kn = k + 1;
    if (tile_c == (kn >> 4)) {
      float e0,e1,e2,e3,e4,e5,e6,e7, prsel, Psel;
      switch (kn & 15) {
#define EXTC(I, G, C) case I: \
  e0=M0_##G.C; e1=M1_##G.C; e2=M2_##G.C; e3=M3_##G.C; \
  e4=M4_##G.C; e5=M5_##G.C; e6=M6_##G.C; e7=M7_##G.C; \
  prsel=PR##G.C; Psel=P##G.C; break;
        EXTC(0,0,x) EXTC(1,0,y) EXTC(2,0,z) EXTC(3,0,w)
        EXTC(4,1,x) EXTC(5,1,y) EXTC(6,1,z) EXTC(7,1,w)
        EXTC(8,2,x) EXTC(9,2,y) EXTC(10,2,z) EXTC(11,2,w)
        EXTC(12,3,x) EXTC(13,3,y) EXTC(14,3,z) EXTC(15,3,w)
#undef EXTC
        default: e0=e1=e2=e3=e4=e5=e6=e7=prsel=Psel=0.f; break;
      }
      // pending k-1 (mp zero at k==0)
      e0 -= mp0*prsel; e1 -= mp1*prsel; e2 -= mp2*prsel; e3 -= mp3*prsel;
      e4 -= mp4*prsel; e5 -= mp5*prsel; e6 -= mp6*prsel; e7 -= mp7*prsel;
      // pending k via publisher's P broadcast (publisher is in this half-wave)
      int srcl = __builtin_amdgcn_readfirstlane((lane & 32) | (int)(pk >> 3));
      float pvk = __uint_as_float((unsigned)__builtin_amdgcn_readlane(
                     (int)__float_as_uint(Psel), srcl));
      e0 -= m0*pvk; e1 -= m1*pvk; e2 -= m2*pvk; e3 -= m3*pvk;
      e4 -= m4*pvk; e5 -= m5*pvk; e6 -= m6*pvk; e7 -= m7*pvk;
      float4 w0; w0.x=e0; w0.y=e1; w0.z=e2; w0.w=e3;
      float4 w1; w1.x=e4; w1.y=e5; w1.z=e6; w1.w=e7;
      *(float4*)&colbuf[buf^1][br]   = w0;
      *(float4*)&colbuf[buf^1][br+4] = w1;
      // search column k+1 within this half-wave
      unsigned key = 0; float val = 0.f;
      REP8(CAND)
      DPAIR(0x111) DPAIR(0x112) DPAIR(0x114) DPAIR(0x118) DPAIR(0x142)
      if (tile_r == 31) { scal_p[buf^1] = key & 255u; scal_v[buf^1] = val; }
    }
    // ---- deferred bulk rank-1 UPD(k-1), off the inter-wave chain ----
    if (havePR) {
#define UPD(R) { float mr = mp##R; \
  M##R##_0.x -= mr*PR0.x; M##R##_0.y -= mr*PR0.y; M##R##_0.z -= mr*PR0.z; M##R##_0.w -= mr*PR0.w; \
  M##R##_1.x -= mr*PR1.x; M##R##_1.y -= mr*PR1.y; M##R##_1.z -= mr*PR1.z; M##R##_1.w -= mr*PR1.w; \
  M##R##_2.x -= mr*PR2.x; M##R##_2.y -= mr*PR2.y; M##R##_2.z -= mr*PR2.z; M##R##_2.w -= mr*PR2.w; \
  M##R##_3.x -= mr*PR3.x; M##R##_3.y -= mr*PR3.y; M##R##_3.z -= mr*PR3.z; M##R##_3.w -= mr*PR3.w; }
      REP8(UPD)
#undef UPD
    }
    mp0=m0; mp1=m1; mp2=m2; mp3=m3; mp4=m4; mp5=m5; mp6=m6; mp7=m7;
    __syncthreads();
  }
#undef CAND
#undef DPAIR
  if (t == 0) g_logs[blockIdx.x] = logf(prod) + (float)esum * 0.69314718055994531f;
}

__global__ void k_final(float* out) { out[0] = g_logs[0] + g_logs[1]; }

// ---------------- launch ----------------
extern "C" void kernel_launch(void* const* d_in, const int* in_sizes, int n_in,
                              void* d_out, int out_size, void* d_ws, size_t ws_size,
                              hipStream_t stream) {
  const float* r     = (const float*)d_in[0];
  const float* a     = (const float*)d_in[1];
  const float* V0_W  = (const float*)d_in[2];
  const float* V0_b  = (const float*)d_in[3];
  const float* Vr_W  = (const float*)d_in[4];
  const float* Vr_b  = (const float*)d_in[5];
  const float* W0_W  = (const float*)d_in[6];
  const float* W0_b  = (const float*)d_in[7];
  const float* Wr_W  = (const float*)d_in[8];
  const float* Wr_b  = (const float*)d_in[9];
  const float* Vhu_W = (const float*)d_in[10];
  const float* Vhu_b = (const float*)d_in[11];
  const float* Vhd_W = (const float*)d_in[12];
  const float* Vhd_b = (const float*)d_in[13];
  const float* wu_W  = (const float*)d_in[14];
  const float* wu_b  = (const float*)d_in[15];
  const float* wd_W  = (const float*)d_in[16];
  const float* wd_b  = (const float*)d_in[17];
  float* out = (float*)d_out;

  k_pgeom<<<512, 256, 0, stream>>>(r, a);
  // entire p-channel (4 layers) in one kernel, means only
  k_pchain<<<2048, 256, 0, stream>>>(W0_W, W0_b, Wr_W, Wr_b, r);
  k_reduce_p<<<1024, 256, 0, stream>>>();

  // s-channel chain (pl selects g_puL/g_pdL layer device-side)
  k_smm<4,64,64><<<dim3(16,8), 256, 0, stream>>>(0, V0_W, V0_b, nullptr, nullptr, 0);
  k_smean<<<2, 256, 0, stream>>>(0);
  k_smm<64,256,256><<<dim3(16,8), 256, 0, stream>>>(1, Vr_W + 0*896*256, Vr_b + 0,
                                                    nullptr, nullptr, 0);
  k_smean<<<2, 256, 0, stream>>>(1);
  k_smm<64,256,256><<<dim3(16,8), 256, 0, stream>>>(2, Vr_W + 1*896*256, Vr_b + 256,
                                                    nullptr, nullptr, 1);
  k_smean<<<2, 256, 0, stream>>>(0);
  k_smm<64,256,256><<<dim3(16,8), 256, 0, stream>>>(3, Vr_W + 2*896*256, Vr_b + 512,
                                                    nullptr, nullptr, 2);
  k_smean<<<2, 256, 0, stream>>>(1);
  // fused heads (u + d)
  k_smm<64,256,256><<<dim3(16,8), 256, 0, stream>>>(4, Vhu_W, Vhu_b, Vhd_W, Vhd_b, 3);
  // fused orbitals (u + d)
  k_smm<0,256,0><<<dim3(16,8), 256, 0, stream>>>(6, wu_W, wu_b, wd_W, wd_b, 0);
  // log|det| x2 and combine
  k_lu<<<2, 512, 0, stream>>>();
  k_final<<<1, 1, 0, stream>>>(out);
}

// Round 14
// 640.748 us; speedup vs baseline: 1.1082x; 1.1082x over previous
//
#include <hip/hip_runtime.h>
#include <hip/hip_bf16.h>

#define NE 512

// ---------------- static device buffers ----------------
__device__ __align__(16) float g_sv0[NE*64];
__device__ __align__(16) float g_sv[2][NE*256];
__device__ __align__(16) float g_pu4[NE*4];
__device__ __align__(16) float g_pd4[NE*4];
__device__ __align__(16) float g_puL[4*NE*64];       // per-layer p-means (u)
__device__ __align__(16) float g_pdL[4*NE*64];       // per-layer p-means (d)
__device__ __align__(16) float g_su0[64];
__device__ __align__(16) float g_sd0[64];
__device__ __align__(16) float g_su[256];
__device__ __align__(16) float g_sd[256];
__device__ __align__(16) float g_part4[4*16*NE*64];  // per-(layer,chunk,j,c) partials
__device__ __align__(16) float g_f[NE];
__device__ __align__(16) float g_hu[256*256];
__device__ __align__(16) float g_hd[256*256];
__device__ __align__(16) float g_orbu[256*256];
__device__ __align__(16) float g_orbd[256*256];
__device__ float g_logs[2];

__device__ __forceinline__ float tanh_fast(float x) {
  float e = __expf(2.f * x);
  return 1.f - 2.f / (e + 1.f);
}

// ---------------- k_front: blocks 0..511 = pgeom(j=bid); 512..2559 = pchain --------
// pgeom and pchain both depend only on (r, a) — fused to overlap and cut a launch.
__global__ __launch_bounds__(256, 4) void k_front(const float* __restrict__ r,
                                                  const float* __restrict__ a,
                                                  const float* __restrict__ W0,
                                                  const float* __restrict__ b0,
                                                  const float* __restrict__ Wr,
                                                  const float* __restrict__ brs) {
  __shared__ __align__(16) float xbuf[4][32*64];     // 32KB (pchain branch)
  __shared__ float red[4][4];                        // (pgeom branch)
  int bid = blockIdx.x, t = threadIdx.x;
  if (bid < 512) {
    // ---- pgeom ----
    int j = bid;
    if (j == 0) {
      for (int h = 0; h < 2; ++h) {
        int e = h*256 + t;
        float rx = r[3*e], ry = r[3*e+1], rz = r[3*e+2];
        float facc = 0.f;
        #pragma unroll
        for (int at = 0; at < 16; ++at) {
          float dx = rx - a[3*at], dy = ry - a[3*at+1], dz = rz - a[3*at+2];
          float len = sqrtf(dx*dx + dy*dy + dz*dz);
          g_sv0[e*64 + 4*at + 0] = dx;
          g_sv0[e*64 + 4*at + 1] = dy;
          g_sv0[e*64 + 4*at + 2] = dz;
          g_sv0[e*64 + 4*at + 3] = len;
          facc += expf(-len);
        }
        g_f[e] = facc;
      }
      __syncthreads();
      if (t < 128) {
        int h = t >> 6, c = t & 63;
        float s = 0.f;
        for (int i = 0; i < 256; ++i) s += g_sv0[(h*256 + i)*64 + c];
        (h ? g_sd0 : g_su0)[c] = s * (1.f/256.f);
      }
      __syncthreads();
    }
    float rjx = r[3*j], rjy = r[3*j+1], rjz = r[3*j+2];
    for (int h = 0; h < 2; ++h) {
      int i = h*256 + t;
      float dx = rjx - r[3*i], dy = rjy - r[3*i+1], dz = rjz - r[3*i+2];
      float ee = (i == j) ? 1.f : 0.f;
      float ex = dx+ee, ey = dy+ee, ez = dz+ee;
      float len = sqrtf(ex*ex + ey*ey + ez*ez);
      float v0 = dx, v1 = dy, v2 = dz, v3 = len;
      #pragma unroll
      for (int m = 1; m < 64; m <<= 1) {
        v0 += __shfl_xor(v0, m); v1 += __shfl_xor(v1, m);
        v2 += __shfl_xor(v2, m); v3 += __shfl_xor(v3, m);
      }
      if ((t & 63) == 0) {
        int wv = t >> 6;
        red[wv][0]=v0; red[wv][1]=v1; red[wv][2]=v2; red[wv][3]=v3;
      }
      __syncthreads();
      if (t == 0) {
        float* dst = h ? g_pd4 : g_pu4;
        #pragma unroll
        for (int c = 0; c < 4; ++c)
          dst[j*4 + c] = (red[0][c]+red[1][c]+red[2][c]+red[3][c]) * (1.f/256.f);
      }
      __syncthreads();
    }
  } else {
    // ---- pchain: 4 layers fully in LDS, means only ----
    int lane = t & 63, wv = t >> 6;
    int gw = (bid - 512)*4 + wv;         // 0..8191
    int j = gw >> 4, chunk = gw & 15;    // 16 chunks of 32 rows
    int i0 = chunk * 32;
    float* xb = xbuf[wv];
    float rjx = r[3*j], rjy = r[3*j+1], rjz = r[3*j+2];
    float macc0 = 0.f, macc1 = 0.f, macc2 = 0.f, macc3 = 0.f;
    {
      float w0 = W0[lane], w1 = W0[64+lane], w2 = W0[128+lane], w3 = W0[192+lane];
      float bb = b0[lane];
      for (int ii = 0; ii < 32; ++ii) {
        int i = i0 + ii;
        float dx = rjx - r[3*i], dy = rjy - r[3*i+1], dz = rjz - r[3*i+2];
        float ee = (i == j) ? 1.f : 0.f;
        float ex = dx+ee, ey = dy+ee, ez = dz+ee;
        float len = sqrtf(ex*ex + ey*ey + ez*ez);
        float y = tanh_fast(bb + dx*w0 + dy*w1 + dz*w2 + len*w3);
        xb[ii*64 + lane] = y;
        macc0 += y;
      }
    }
    for (int l = 0; l < 3; ++l) {
      const float* W = Wr + l*4096;
      float wcol[64];
      #pragma unroll
      for (int k = 0; k < 64; ++k) wcol[k] = W[k*64 + lane];
      float bb = brs[l*64 + lane];
      float mac = 0.f;
      for (int ii = 0; ii < 32; ++ii) {
        const float* row = &xb[ii*64];
        float x = row[lane];
        float acc = bb;
        #pragma unroll
        for (int g = 0; g < 16; ++g) {
          float4 pv = *(const float4*)&row[4*g];     // wave-uniform broadcast
          acc += pv.x*wcol[4*g] + pv.y*wcol[4*g+1] + pv.z*wcol[4*g+2] + pv.w*wcol[4*g+3];
        }
        float y = tanh_fast(acc) + x;
        xb[ii*64 + lane] = y;
        mac += y;
      }
      if (l == 0) macc1 = mac;
      else if (l == 1) macc2 = mac;
      else macc3 = mac;
    }
    int base = chunk*(NE*64) + j*64 + lane;
    g_part4[0*(16*NE*64) + base] = macc0;
    g_part4[1*(16*NE*64) + base] = macc1;
    g_part4[2*(16*NE*64) + base] = macc2;
    g_part4[3*(16*NE*64) + base] = macc3;
  }
}

// ---------------- finalize all 4 layers' p-means ----------------
__global__ __launch_bounds__(256) void k_reduce_p() {
  int idx = blockIdx.x*256 + threadIdx.x;   // 0..262143
  int l = idx >> 16;
  int rem = idx & 65535;
  int half = rem >> 15;
  int r2 = rem & 32767;
  int j = r2 >> 6, c = r2 & 63;
  const float* pp = g_part4 + l*(16*NE*64) + half*(8*NE*64) + j*64 + c;
  float s = 0.f;
  #pragma unroll
  for (int ch = 0; ch < 8; ++ch) s += pp[ch*(NE*64)];
  (half ? g_pdL : g_puL)[l*(NE*64) + j*64 + c] = s * (1.f/256.f);
}

// ---------------- s_v column means ----------------
__global__ __launch_bounds__(256) void k_smean(int svsel) {
  int h = blockIdx.x, t = threadIdx.x;
  const float* sv = g_sv[svsel];
  float s = 0.f;
  for (int i = 0; i < 256; ++i) s += sv[(h*256 + i)*256 + t];
  (h ? g_sd : g_su)[t] = s * (1.f/256.f);
}

// ---------------- s-channel matmul ----------------
// which: 0=layer0, 1..3=layer l, 4=FUSED heads (grp=rg>>3), 6=FUSED orbitals
template<int PUK, int SVK, int MEANK>
__global__ __launch_bounds__(256) void k_smm(int which, const float* __restrict__ W,
                                             const float* __restrict__ Wb,
                                             const float* __restrict__ W2,
                                             const float* __restrict__ Wb2,
                                             int pl) {
  constexpr int MAINK = 2*PUK + SVK;
  __shared__ __align__(16) float wsl[MAINK*32];
  __shared__ float insl[32*(MAINK+1)];
  __shared__ float biasv[32];
  __shared__ float bred[256];
  const float *pu_p=nullptr, *pd_p=nullptr, *sv_p=nullptr, *su_p=nullptr, *sd_p=nullptr;
  const float *res_p=nullptr, *rs_p=nullptr;
  float* out_p = nullptr;
  int t = threadIdx.x;
  int rg = blockIdx.x, cg = blockIdx.y;
  int grp = 0, rgl = rg;
  if (which >= 4) { grp = rg >> 3; rgl = rg & 7; }
  const float* Wsel = (which >= 4 && grp) ? W2 : W;
  const float* Wbsel = (which >= 4 && grp) ? Wb2 : Wb;
  int in_base = 0, dotanh = 1;
  switch (which) {
    case 0: pu_p=g_pu4; pd_p=g_pd4; su_p=g_su0; sd_p=g_sd0; sv_p=g_sv0;
            out_p=g_sv[0]; in_base=rg*32; break;
    case 1: case 2: case 3:
      pu_p=g_puL + pl*(NE*64); pd_p=g_pdL + pl*(NE*64); su_p=g_su; sd_p=g_sd;
      sv_p=g_sv[(which+1)&1]; res_p=sv_p; out_p=g_sv[which&1]; in_base=rg*32; break;
    case 4: pu_p=g_puL + pl*(NE*64); pd_p=g_pdL + pl*(NE*64); su_p=g_su; sd_p=g_sd;
            sv_p=g_sv[1]; out_p = grp ? g_hd : g_hu; in_base = grp*256 + rgl*32; break;
    default: sv_p = grp ? g_hd : g_hu; out_p = grp ? g_orbd : g_orbu;
             rs_p = g_f + grp*256; in_base = rgl*32; dotanh = 0; break;
  }
  int out_base = (which >= 4) ? rgl*32 : rg*32;
  int col0 = cg * 32;
  for (int idx = t; idx < MAINK*32; idx += 256) {
    int c = idx >> 5, cl = idx & 31;
    wsl[idx] = Wsel[(2*MEANK + c)*256 + col0 + cl];
  }
  for (int rr = 0; rr < 32; ++rr) {
    int row = in_base + rr;
    for (int c = t; c < MAINK; c += 256) {
      float v;
      if (c < PUK) v = pu_p[row*PUK + c];
      else if (c < 2*PUK) v = pd_p[row*PUK + (c - PUK)];
      else v = sv_p[row*SVK + (c - 2*PUK)];
      insl[rr*(MAINK+1) + c] = v;
    }
  }
  {
    int pcol = t & 31, ps = t >> 5;
    float bacc = 0.f;
    if (MEANK > 0) {
      for (int c = ps; c < MEANK; c += 8)
        bacc += su_p[c]*Wsel[c*256 + col0 + pcol] + sd_p[c]*Wsel[(MEANK + c)*256 + col0 + pcol];
    }
    bred[ps*32 + pcol] = bacc;
  }
  __syncthreads();
  if (t < 32) {
    float s = Wbsel[col0 + t];
    #pragma unroll
    for (int p8 = 0; p8 < 8; ++p8) s += bred[p8*32 + t];
    biasv[t] = s;
  }
  __syncthreads();
  int c4 = t & 7, rl = t >> 3;
  float a0 = biasv[4*c4], a1 = biasv[4*c4+1], a2 = biasv[4*c4+2], a3 = biasv[4*c4+3];
  const float* inrow = &insl[rl*(MAINK+1)];
  #pragma unroll 4
  for (int c = 0; c < MAINK; ++c) {
    float iv = inrow[c];
    float4 wv = *(const float4*)&wsl[c*32 + 4*c4];
    a0 += iv*wv.x; a1 += iv*wv.y; a2 += iv*wv.z; a3 += iv*wv.w;
  }
  int rowA = out_base + rl;
  int col = col0 + 4*c4;
  if (dotanh) { a0=tanh_fast(a0); a1=tanh_fast(a1); a2=tanh_fast(a2); a3=tanh_fast(a3); }
  if (res_p) {
    float4 rv = *(const float4*)&res_p[rowA*256 + col];
    a0 += rv.x; a1 += rv.y; a2 += rv.z; a3 += rv.w;
  }
  if (rs_p) { float fsc = rs_p[rowA]; a0*=fsc; a1*=fsc; a2*=fsc; a3*=fsc; }
  float4 ov; ov.x=a0; ov.y=a1; ov.z=a2; ov.w=a3;
  *(float4*)&out_p[rowA*256 + col] = ov;
}

// ---------------- register-resident LU, v8 (best measured: 249us, R10) ----------------
// R13 lesson: v9's deferred-update restructure regressed (321us, 261K bank conflicts,
// VGPR 104); v8.1's readlane+deferred-renorm also slightly worse (260). Exact v8.
#define REP8(M) M(0) M(1) M(2) M(3) M(4) M(5) M(6) M(7)
#define DPPMAX(v, CTRL) { unsigned _o = (unsigned)__builtin_amdgcn_update_dpp(0, (int)(v), CTRL, 0xf, 0xf, true); \
                          (v) = (v) > _o ? (v) : _o; }

__global__ __launch_bounds__(512, 2) void k_lu() {
  __shared__ __align__(16) float colbuf[2][256];
  __shared__ __align__(16) float prowbuf[2][16*20];
  const float* A = (blockIdx.x == 0) ? g_orbu : g_orbd;
  int t = threadIdx.x;
  int tile_c = t >> 5;        // 0..15 -> cols 16*tile_c .. +15
  int tile_r = t & 31;        // 0..31 -> rows 8*tile_r .. +7
  int lane = t & 63;
  int br = tile_r * 8;
  int pb = tile_c * 20;
  const float4* Ap = (const float4*)(A + br*256 + tile_c*16);
#define DECLROW(R) float4 M##R##_0 = Ap[R*64+0], M##R##_1 = Ap[R*64+1], \
                          M##R##_2 = Ap[R*64+2], M##R##_3 = Ap[R*64+3];
  REP8(DECLROW)
#undef DECLROW
  unsigned um = 0;
  if (tile_c == 0) {
#define INIT0(R) colbuf[0][br+R] = M##R##_0.x;
    REP8(INIT0)
#undef INIT0
  }
  __syncthreads();
  float prod = 1.f;
  int esum = 0;
  float m0=0,m1=0,m2=0,m3=0,m4=0,m5=0,m6=0,m7=0;
  for (int k = 0; k < 256; ++k) {
    const float* cbin = colbuf[k & 1];
    float4 cv = *(const float4*)&cbin[4*lane];
    float4 ca = *(const float4*)&cbin[br];
    float4 cb2 = *(const float4*)&cbin[br+4];
    bool aliveU = (tile_c*16 + 15) >= k;
    if (k > 0 && aliveU) {
      const float* pwp = &prowbuf[(k-1) & 1][pb];
      float4 P0 = *(const float4*)&pwp[0];
      float4 P1 = *(const float4*)&pwp[4];
      float4 P2 = *(const float4*)&pwp[8];
      float4 P3 = *(const float4*)&pwp[12];
#define UPD(R) { float mr = m##R; \
  M##R##_0.x -= mr*P0.x; M##R##_0.y -= mr*P0.y; M##R##_0.z -= mr*P0.z; M##R##_0.w -= mr*P0.w; \
  M##R##_1.x -= mr*P1.x; M##R##_1.y -= mr*P1.y; M##R##_1.z -= mr*P1.z; M##R##_1.w -= mr*P1.w; \
  M##R##_2.x -= mr*P2.x; M##R##_2.y -= mr*P2.y; M##R##_2.z -= mr*P2.z; M##R##_2.w -= mr*P2.w; \
  M##R##_3.x -= mr*P3.x; M##R##_3.y -= mr*P3.y; M##R##_3.z -= mr*P3.z; M##R##_3.w -= mr*P3.w; }
      REP8(UPD)
#undef UPD
    }
    unsigned b0 = (um & 1u) ? 0u : ((__float_as_uint(fabsf(cv.x)) & 0xFFFFFF00u) | (unsigned)(4*lane+0));
    unsigned b1 = (um & 2u) ? 0u : ((__float_as_uint(fabsf(cv.y)) & 0xFFFFFF00u) | (unsigned)(4*lane+1));
    unsigned b2 = (um & 4u) ? 0u : ((__float_as_uint(fabsf(cv.z)) & 0xFFFFFF00u) | (unsigned)(4*lane+2));
    unsigned b3 = (um & 8u) ? 0u : ((__float_as_uint(fabsf(cv.w)) & 0xFFFFFF00u) | (unsigned)(4*lane+3));
    unsigned bb = max(max(b0,b1), max(b2,b3));
    DPPMAX(bb, 0x111) DPPMAX(bb, 0x112) DPPMAX(bb, 0x114) DPPMAX(bb, 0x118)
    DPPMAX(bb, 0x142) DPPMAX(bb, 0x143)
    bb = (unsigned)__builtin_amdgcn_readlane((int)bb, 63);
    int p = (int)(bb & 255u);
    int wl = p >> 2, cc = p & 3;
    unsigned px = (unsigned)__builtin_amdgcn_readlane((int)__float_as_uint(cv.x), wl);
    unsigned py = (unsigned)__builtin_amdgcn_readlane((int)__float_as_uint(cv.y), wl);
    unsigned pz = (unsigned)__builtin_amdgcn_readlane((int)__float_as_uint(cv.z), wl);
    unsigned pw = (unsigned)__builtin_amdgcn_readlane((int)__float_as_uint(cv.w), wl);
    float piv = __uint_as_float(cc==0 ? px : cc==1 ? py : cc==2 ? pz : pw);
    int ee; float mant = frexpf(fabsf(piv), &ee);
    prod *= mant; esum += ee;
    int e2; prod = frexpf(prod, &e2); esum += e2;   // keep prod in [0.25,1)
    if (wl == lane) um |= 1u << cc;
    if (k == 255) break;
    float rp = 1.0f / piv;
    m0 = ca.x*rp; m1 = ca.y*rp; m2 = ca.z*rp; m3 = ca.w*rp;
    m4 = cb2.x*rp; m5 = cb2.y*rp; m6 = cb2.z*rp; m7 = cb2.w*rp;
    bool aliveK = (tile_c*16 + 15) > k;
    if (aliveK && tile_r == (p >> 3)) {
      float* pw_ = &prowbuf[k & 1][pb];
      switch (p & 7) {
#define PUBC(R) case R: *(float4*)&pw_[0] = M##R##_0; *(float4*)&pw_[4] = M##R##_1; \
                        *(float4*)&pw_[8] = M##R##_2; *(float4*)&pw_[12] = M##R##_3; break;
        REP8(PUBC)
#undef PUBC
      }
    }
    int kn = k + 1;
    if (tile_c == (kn >> 4)) {
      float e0,e1,e2b,e3,e4,e5,e6,e7;
      switch (kn & 15) {
#define EXTC(I, G, C) case I: e0=M0_##G.C; e1=M1_##G.C; e2b=M2_##G.C; e3=M3_##G.C; \
                              e4=M4_##G.C; e5=M5_##G.C; e6=M6_##G.C; e7=M7_##G.C; break;
        EXTC(0,0,x) EXTC(1,0,y) EXTC(2,0,z) EXTC(3,0,w)
        EXTC(4,1,x) EXTC(5,1,y) EXTC(6,1,z) EXTC(7,1,w)
        EXTC(8,2,x) EXTC(9,2,y) EXTC(10,2,z) EXTC(11,2,w)
        EXTC(12,3,x) EXTC(13,3,y) EXTC(14,3,z) EXTC(15,3,w)
#undef EXTC
      }
      float sel;
      switch (p & 7) {
        case 0: sel = e0; break; case 1: sel = e1; break;
        case 2: sel = e2b; break; case 3: sel = e3; break;
        case 4: sel = e4; break; case 5: sel = e5; break;
        case 6: sel = e6; break; default: sel = e7; break;
      }
      float pv = __shfl(sel, (tile_c & 1)*32 + (p >> 3), 64);
      float4 w0, w1;
      w0.x = e0 - m0*pv; w0.y = e1 - m1*pv; w0.z = e2b - m2*pv; w0.w = e3 - m3*pv;
      w1.x = e4 - m4*pv; w1.y = e5 - m5*pv; w1.z = e6 - m6*pv; w1.w = e7 - m7*pv;
      *(float4*)&colbuf[kn & 1][br] = w0;
      *(float4*)&colbuf[kn & 1][br+4] = w1;
    }
    __syncthreads();
  }
  if (t == 0) g_logs[blockIdx.x] = logf(prod) + (float)esum * 0.69314718055994531f;
}

__global__ void k_final(float* out) { out[0] = g_logs[0] + g_logs[1]; }

// ---------------- launch ----------------
extern "C" void kernel_launch(void* const* d_in, const int* in_sizes, int n_in,
                              void* d_out, int out_size, void* d_ws, size_t ws_size,
                              hipStream_t stream) {
  const float* r     = (const float*)d_in[0];
  const float* a     = (const float*)d_in[1];
  const float* V0_W  = (const float*)d_in[2];
  const float* V0_b  = (const float*)d_in[3];
  const float* Vr_W  = (const float*)d_in[4];
  const float* Vr_b  = (const float*)d_in[5];
  const float* W0_W  = (const float*)d_in[6];
  const float* W0_b  = (const float*)d_in[7];
  const float* Wr_W  = (const float*)d_in[8];
  const float* Wr_b  = (const float*)d_in[9];
  const float* Vhu_W = (const float*)d_in[10];
  const float* Vhu_b = (const float*)d_in[11];
  const float* Vhd_W = (const float*)d_in[12];
  const float* Vhd_b = (const float*)d_in[13];
  const float* wu_W  = (const float*)d_in[14];
  const float* wu_b  = (const float*)d_in[15];
  const float* wd_W  = (const float*)d_in[16];
  const float* wd_b  = (const float*)d_in[17];
  float* out = (float*)d_out;

  // fused pgeom + full p-chain
  k_front<<<2560, 256, 0, stream>>>(r, a, W0_W, W0_b, Wr_W, Wr_b);
  k_reduce_p<<<1024, 256, 0, stream>>>();

  // s-channel chain (pl selects g_puL/g_pdL layer device-side)
  k_smm<4,64,64><<<dim3(16,8), 256, 0, stream>>>(0, V0_W, V0_b, nullptr, nullptr, 0);
  k_smean<<<2, 256, 0, stream>>>(0);
  k_smm<64,256,256><<<dim3(16,8), 256, 0, stream>>>(1, Vr_W + 0*896*256, Vr_b + 0,
                                                    nullptr, nullptr, 0);
  k_smean<<<2, 256, 0, stream>>>(1);
  k_smm<64,256,256><<<dim3(16,8), 256, 0, stream>>>(2, Vr_W + 1*896*256, Vr_b + 256,
                                                    nullptr, nullptr, 1);
  k_smean<<<2, 256, 0, stream>>>(0);
  k_smm<64,256,256><<<dim3(16,8), 256, 0, stream>>>(3, Vr_W + 2*896*256, Vr_b + 512,
                                                    nullptr, nullptr, 2);
  k_smean<<<2, 256, 0, stream>>>(1);
  // fused heads (u + d)
  k_smm<64,256,256><<<dim3(16,8), 256, 0, stream>>>(4, Vhu_W, Vhu_b, Vhd_W, Vhd_b, 3);
  // fused orbitals (u + d)
  k_smm<0,256,0><<<dim3(16,8), 256, 0, stream>>>(6, wu_W, wu_b, wd_W, wd_b, 0);
  // log|det| x2 and combine
  k_lu<<<2, 512, 0, stream>>>();
  k_final<<<1, 1, 0, stream>>>(out);
}